// Round 16
// baseline (367.445 us; speedup 1.0000x reference)
//
#include <hip/hip_runtime.h>

typedef __attribute__((ext_vector_type(8))) short bf16x8;
typedef __attribute__((ext_vector_type(4))) float f32x4;

__device__ __forceinline__ unsigned short f2bf(float f) {
  unsigned u = __float_as_uint(f);
  u += 0x7fff + ((u >> 16) & 1);
  return (unsigned short)(u >> 16);
}
__device__ __forceinline__ float bf2f(unsigned short h) {
  return __uint_as_float(((unsigned)h) << 16);
}

__device__ __forceinline__ void gload_lds16(const void* g, void* l) {
  __builtin_amdgcn_global_load_lds((const __attribute__((address_space(1))) void*)g,
                                   (__attribute__((address_space(3))) void*)l, 16, 0, 0);
}

// raw s_barrier + compiler memory fence (no sched_barrier pinning — m141)
__device__ __forceinline__ void pbar() {
  asm volatile("" ::: "memory");
  __builtin_amdgcn_s_barrier();
  asm volatile("" ::: "memory");
}

// ---------------- halo zeroing ----------------
__global__ __launch_bounds__(256) void halo_k(unsigned short* __restrict__ h1,
                                              unsigned short* __restrict__ h2,
                                              unsigned short* __restrict__ h3,
                                              unsigned short* __restrict__ h4) {
  int pid = blockIdx.x * 2 + (threadIdx.x >> 7);  // [0, 12416)
  int co = threadIdx.x & 127;
  unsigned short* buf;
  int b, e, SP;
  if (pid < 8256) {
    buf = (pid < 4128) ? h1 : h4;
    int rel = (pid < 4128) ? pid : pid - 4128;
    b = rel / 516; e = rel % 516; SP = 130;
    int y, x;
    if (e < 130) { y = 0; x = e; }
    else if (e < 260) { y = 129; x = e - 130; }
    else if (e < 388) { y = 1 + (e - 260); x = 0; }
    else { y = 1 + (e - 388); x = 129; }
    buf[(((size_t)(b * SP + y)) * SP + x) * 128 + co] = 0;
  } else {
    buf = (pid < 10336) ? h2 : h3;
    int rel = pid - ((pid < 10336) ? 8256 : 10336);
    b = rel / 260; e = rel % 260; SP = 66;
    int y, x;
    if (e < 66) { y = 0; x = e; }
    else if (e < 132) { y = 65; x = e - 66; }
    else if (e < 196) { y = 1 + (e - 132); x = 0; }
    else { y = 1 + (e - 196); x = 65; }
    buf[(((size_t)(b * SP + y)) * SP + x) * 128 + co] = 0;
  }
}

// ---------------- coalesced transpose weight packing ----------------
__global__ __launch_bounds__(256) void packT_k(
    const float* __restrict__ ew2, const float* __restrict__ ew3,
    const float* __restrict__ dw1, const float* __restrict__ dw2,
    unsigned short* __restrict__ bt2, unsigned short* __restrict__ bt3,
    unsigned short* __restrict__ btw1, unsigned short* __restrict__ btd2) {
  __shared__ float sT[128 * 17 + 16];
  const int tid = threadIdx.x;
  const int blk = blockIdx.x;
  if (blk < 2048) {
    const int co = blk;
    const float* src = ew3 + (size_t)co * 2048;
    const int ci = tid >> 1, k0 = (tid & 1) * 8;
#pragma unroll
    for (int e = 0; e < 8; ++e) sT[ci * 17 + k0 + e] = src[tid * 8 + e];
    __syncthreads();
    const int kko = tid >> 4, ci0 = (tid & 15) * 8;
    unsigned short v[8];
#pragma unroll
    for (int e = 0; e < 8; ++e) v[e] = f2bf(sT[(ci0 + e) * 17 + kko]);
    *(bf16x8*)(bt3 + (size_t)co * 2048 + tid * 8) = *(bf16x8*)v;
  } else if (blk < 4096) {
    const int r = blk - 2048;
    const int co = r & 127, c0 = (r >> 7) << 7;
    const int ci = tid >> 1, t0 = (tid & 1) * 8;
    const float* src = dw1 + ((size_t)(c0 + ci) * 128 + co) * 16 + t0;
#pragma unroll
    for (int e = 0; e < 8; ++e) sT[ci * 17 + t0 + e] = src[e];
    __syncthreads();
    const int t = tid >> 4, ci0 = (tid & 15) * 8;
    unsigned short v[8];
#pragma unroll
    for (int e = 0; e < 8; ++e) v[e] = f2bf(sT[(ci0 + e) * 17 + t]);
    *(bf16x8*)(btw1 + (size_t)(t * 128 + co) * 2048 + c0 + ci0) = *(bf16x8*)v;
  } else if (blk < 4224) {
    const int co = blk - 4096;
    const float* src = ew2 + (size_t)co * 2048;
    const int ci = tid >> 1, k0 = (tid & 1) * 8;
#pragma unroll
    for (int e = 0; e < 8; ++e) sT[ci * 17 + k0 + e] = src[tid * 8 + e];
    __syncthreads();
    const int kko = tid >> 4, ci0 = (tid & 15) * 8;
    unsigned short v[8];
#pragma unroll
    for (int e = 0; e < 8; ++e) v[e] = f2bf(sT[(ci0 + e) * 17 + kko]);
    *(bf16x8*)(bt2 + (size_t)co * 2048 + tid * 8) = *(bf16x8*)v;
  } else {
    const int co = blk - 4224;
    const int ci = tid >> 1, t0 = (tid & 1) * 8;
    const float* src = dw2 + ((size_t)ci * 128 + co) * 16 + t0;
#pragma unroll
    for (int e = 0; e < 8; ++e) sT[ci * 17 + t0 + e] = src[e];
    __syncthreads();
    const int zt = tid >> 4, ci0 = (tid & 15) * 8;
    const int z = zt >> 2, tp = zt & 3;
    const int py = z >> 1, px = z & 1, ty = tp >> 1, tx = tp & 1;
    const int kk = (2 * ty + 1 - py) * 4 + (2 * tx + 1 - px);
    unsigned short v[8];
#pragma unroll
    for (int e = 0; e < 8; ++e) v[e] = f2bf(sT[(ci0 + e) * 17 + kk]);
    *(bf16x8*)(btd2 + ((size_t)(z * 128 + co) * 4 + tp) * 128 + ci0) = *(bf16x8*)v;
  }
}

// ---------------- codebook pack (+wd3 in last block) ----------------
__global__ __launch_bounds__(256) void pack_cb(const float* __restrict__ cb,
                                               const float* __restrict__ dw3,
                                               unsigned short* __restrict__ cbb,
                                               float* __restrict__ cnorm,
                                               float* __restrict__ wd3) {
  int r = blockIdx.x;
  if (r == 1024) {
#pragma unroll
    for (int e = 0; e < 8; ++e) {
      int j = threadIdx.x * 8 + e;  // [0,2048)
      int ci = j & 127, t = (j >> 7) & 3, z = j >> 9;
      int py = z >> 1, px = z & 1, ty = t >> 1, tx = t & 1;
      int ky = 2 * ty + 1 - py, kx = 2 * tx + 1 - px;
      wd3[j] = dw3[ci * 16 + ky * 4 + kx];
    }
    return;
  }
  const float* src = cb + (size_t)r * 2048;
  float s = 0.f;
  for (int i = threadIdx.x; i < 2048; i += 256) {
    float v = src[i];
    cbb[(size_t)r * 2048 + i] = f2bf(v);
    s += v * v;
  }
  __shared__ float red[4];
  for (int off = 32; off > 0; off >>= 1) s += __shfl_down(s, off, 64);
  int lane = threadIdx.x & 63, wid = threadIdx.x >> 6;
  if (lane == 0) red[wid] = s;
  __syncthreads();
  if (threadIdx.x == 0) cnorm[r] = red[0] + red[1] + red[2] + red[3];
}

// ---------------- conv1 (3->128, direct) ----------------
__global__ __launch_bounds__(256) void conv1_k(const float* __restrict__ x,
                                               const float* __restrict__ w1,
                                               const float* __restrict__ b1,
                                               unsigned short* __restrict__ h1) {
  __shared__ float sIn[3][4][258];
  int b = blockIdx.x >> 7, y = blockIdx.x & 127;
  for (int i = threadIdx.x; i < 3 * 4 * 258; i += 256) {
    int c = i / (4 * 258);
    int rr = (i / 258) % 4;
    int col = i % 258;
    int iy = 2 * y - 1 + rr;
    int ix = col - 1;
    float v = (iy >= 0 && iy < 256 && ix >= 0 && ix < 256)
                  ? x[((size_t)(b * 3 + c) * 256 + iy) * 256 + ix] : 0.f;
    sIn[c][rr][col] = v;
  }
  __syncthreads();
  int co = threadIdx.x & 127, xh = threadIdx.x >> 7;
  float w[3][4][4];
#pragma unroll
  for (int c = 0; c < 3; ++c)
#pragma unroll
    for (int ky = 0; ky < 4; ++ky)
#pragma unroll
      for (int kx = 0; kx < 4; ++kx)
        w[c][ky][kx] = w1[(((size_t)co * 3 + c) * 4 + ky) * 4 + kx];
  float bb = b1[co];
  for (int xi = 0; xi < 64; ++xi) {
    int xx = xh * 64 + xi;
    float acc = bb;
#pragma unroll
    for (int c = 0; c < 3; ++c)
#pragma unroll
      for (int ky = 0; ky < 4; ++ky)
#pragma unroll
        for (int kx = 0; kx < 4; ++kx)
          acc += sIn[c][ky][2 * xx + kx] * w[c][ky][kx];
    acc = acc > 0.f ? acc : 0.f;
    h1[((size_t)(b * 130 + y + 1) * 130 + (xx + 1)) * 128 + co] = f2bf(acc);
  }
}

// ---------------- generic implicit-GEMM defs ----------------
#define GM_CONV 0
#define GM_DECONV 1
#define GM_FLAT 2
#define EP_PM 0
#define EP_FLATBF 1
#define EP_F32 2

struct GP {
  const unsigned short* A;
  const unsigned short* Bt;
  const float* bias;
  void* out;
  int Klen, Clog;
  int MXlog, MYlog;
  int WPin, strideBA;
  int HPo, WPo;
  int Nout;
  int BrowStride;
  int BclassStride;
  int classLog;
  int TPC;
  int outZ;
};

// ---------------- 2-barrier GEMM (deconv2) ----------------
template <int BM, int GM, int EP, int RELU>
__global__ __launch_bounds__(256) void gemm_k(GP p) {
  constexpr int MFR = BM / 32;
  constexpr int CA = BM / 32;
  const int tid = threadIdx.x;
  const int lane = tid & 63;
  const int wid = tid >> 6;
  const int m0 = blockIdx.x * BM;
  const int n0 = blockIdx.y * 128;
  const int zAll = blockIdx.z;
  const int zc = zAll & ((1 << p.classLog) - 1);
  const int chunk = zAll >> p.classLog;
  const int py = zc >> 1, px = zc & 1;

  __shared__ __align__(16) unsigned short sA[BM * 64];
  __shared__ __align__(16) unsigned short sB[128 * 64];

  const unsigned short* Bt = p.Bt + (size_t)zc * p.BclassStride;
  const int C = 1 << p.Clog;
  const int tb = chunk * p.TPC;
  const int chunkOff = tb << p.Clog;
  const int sw = ((lane & 7) ^ (lane >> 3)) * 8;

  int rcA[CA];
#pragma unroll
  for (int i = 0; i < CA; ++i) {
    int r = (wid * CA + i) * 8 + (lane >> 3);
    int m = m0 + r;
    if (GM == GM_FLAT) {
      rcA[i] = m * p.Klen;
    } else {
      int mx = m & ((1 << p.MXlog) - 1);
      int my = (m >> p.MXlog) & ((1 << p.MYlog) - 1);
      int b = m >> (p.MXlog + p.MYlog);
      if (GM == GM_CONV)
        rcA[i] = b * p.strideBA + ((2 * my) * p.WPin + 2 * mx) * C;
      else
        rcA[i] = b * p.strideBA + ((my + 1) * p.WPin + (mx + 1)) * C;
    }
  }
  int rcB[4];
#pragma unroll
  for (int i = 0; i < 4; ++i) {
    int r = (wid * 4 + i) * 8 + (lane >> 3);
    rcB[i] = (n0 + r) * p.BrowStride;
  }

  f32x4 acc[MFR][4];
#pragma unroll
  for (int a = 0; a < MFR; ++a)
#pragma unroll
    for (int b = 0; b < 4; ++b) acc[a][b] = (f32x4){0.f, 0.f, 0.f, 0.f};

  const int nsteps = p.Klen >> 6;
  for (int ks = 0; ks < nsteps; ++ks) {
    const int k0 = ks << 6;
    int tap = 0;
    if (GM == GM_CONV) {
      int t = tb + (k0 >> p.Clog);
      tap = ((t >> 2) * p.WPin + (t & 3)) * C;
    } else if (GM == GM_DECONV) {
      int t = tb + (k0 >> p.Clog);
      int ty = t >> 1, tx = t & 1;
      tap = ((py - ty) * p.WPin + (px - tx)) * C;
    }
    const int ci0 = k0 & (C - 1);
    const int aoff = tap + ci0 + sw;
#pragma unroll
    for (int i = 0; i < CA; ++i)
      gload_lds16(p.A + rcA[i] + aoff, &sA[(wid * CA + i) * 512]);
#pragma unroll
    for (int i = 0; i < 4; ++i)
      gload_lds16(Bt + rcB[i] + chunkOff + k0 + sw, &sB[(wid * 4 + i) * 512]);
    __syncthreads();

#pragma unroll
    for (int kk = 0; kk < 2; ++kk) {
      bf16x8 af[MFR], bfv[4];
#pragma unroll
      for (int mf = 0; mf < MFR; ++mf) {
        int row = (wid >> 1) * (BM / 2) + mf * 16 + (lane & 15);
        int col = (kk * 64 + ((lane >> 4) << 4)) ^ ((row & 7) << 4);
        af[mf] = *(const bf16x8*)((const char*)sA + row * 128 + col);
      }
#pragma unroll
      for (int nf = 0; nf < 4; ++nf) {
        int row = (wid & 1) * 64 + nf * 16 + (lane & 15);
        int col = (kk * 64 + ((lane >> 4) << 4)) ^ ((row & 7) << 4);
        bfv[nf] = *(const bf16x8*)((const char*)sB + row * 128 + col);
      }
#pragma unroll
      for (int mf = 0; mf < MFR; ++mf)
#pragma unroll
        for (int nf = 0; nf < 4; ++nf)
          acc[mf][nf] = __builtin_amdgcn_mfma_f32_16x16x32_bf16(
              af[mf], bfv[nf], acc[mf][nf], 0, 0, 0);
    }
    __syncthreads();
  }

  const int wr = wid >> 1, wc = wid & 1;
#pragma unroll
  for (int mf = 0; mf < MFR; ++mf) {
#pragma unroll
    for (int j = 0; j < 4; ++j) {
      int row = m0 + wr * (BM / 2) + mf * 16 + ((lane >> 4) << 2) + j;
      int b = 0, my = 0, mx = 0;
      if (EP == EP_PM) {
        mx = row & ((1 << p.MXlog) - 1);
        my = (row >> p.MXlog) & ((1 << p.MYlog) - 1);
        b = row >> (p.MXlog + p.MYlog);
      }
#pragma unroll
      for (int nf = 0; nf < 4; ++nf) {
        int col = n0 + wc * 64 + nf * 16 + (lane & 15);
        float v = acc[mf][nf][j];
        if (EP == EP_PM || EP == EP_FLATBF) v += p.bias[col];
        if (RELU) v = v > 0.f ? v : 0.f;
        if (EP == EP_F32) {
          ((float*)p.out)[(size_t)row * p.Nout + col] = v;
        } else if (EP == EP_FLATBF) {
          ((unsigned short*)p.out)[(size_t)row * p.Nout + col] = f2bf(v);
        } else {
          int oy, ox;
          if (GM == GM_DECONV) {
            oy = 2 * my + py + 1;
            ox = 2 * mx + px + 1;
          } else {
            oy = my + 1;
            ox = mx + 1;
          }
          ((unsigned short*)p.out)[((size_t)(b * p.HPo + oy) * p.WPo + ox) * 128 + col] =
              f2bf(v);
        }
      }
    }
  }
}

// ---------------- 2-phase double-buffered BM=64 GEMM (conv2, V) ----------------
template <int GM, int EP, int RELU>
__global__ __launch_bounds__(256) void gemmp_k(GP p) {
  constexpr int BM = 64;
  constexpr int MFR = 2;
  constexpr int CA = 2;
  const int tid = threadIdx.x;
  const int lane = tid & 63;
  const int wid = tid >> 6;
  const int m0 = blockIdx.x * BM;
  const int n0 = blockIdx.y * 128;

  __shared__ __align__(16) unsigned short sA[2][BM * 64];
  __shared__ __align__(16) unsigned short sB[2][128 * 64];

  const unsigned short* Bt = p.Bt;
  const int C = 1 << p.Clog;
  const int sw = ((lane & 7) ^ (lane >> 3)) * 8;

  int rcA[CA];
#pragma unroll
  for (int i = 0; i < CA; ++i) {
    int r = (wid * CA + i) * 8 + (lane >> 3);
    int m = m0 + r;
    if (GM == GM_FLAT) {
      rcA[i] = m * p.Klen;
    } else {
      int mx = m & ((1 << p.MXlog) - 1);
      int my = (m >> p.MXlog) & ((1 << p.MYlog) - 1);
      int b = m >> (p.MXlog + p.MYlog);
      rcA[i] = b * p.strideBA + ((2 * my) * p.WPin + 2 * mx) * C;
    }
  }
  int rcB[4];
#pragma unroll
  for (int i = 0; i < 4; ++i) {
    int r = (wid * 4 + i) * 8 + (lane >> 3);
    rcB[i] = (n0 + r) * p.BrowStride;
  }

  const int nsteps = p.Klen >> 6;

  auto stageK = [&](int ks, int bs) {
    if (ks >= nsteps) return;
    const int k0 = ks << 6;
    int tap = 0;
    if (GM == GM_CONV) {
      int t = k0 >> p.Clog;
      tap = ((t >> 2) * p.WPin + (t & 3)) * C;
    }
    const int aoff = tap + (k0 & (C - 1)) + sw;
#pragma unroll
    for (int i = 0; i < CA; ++i)
      gload_lds16(p.A + rcA[i] + aoff, &sA[bs][(wid * CA + i) * 512]);
#pragma unroll
    for (int i = 0; i < 4; ++i)
      gload_lds16(Bt + rcB[i] + k0 + sw, &sB[bs][(wid * 4 + i) * 512]);
  };

  f32x4 acc[MFR][4];
#pragma unroll
  for (int a = 0; a < MFR; ++a)
#pragma unroll
    for (int b = 0; b < 4; ++b) acc[a][b] = (f32x4){0.f, 0.f, 0.f, 0.f};

  stageK(0, 0);
  asm volatile("s_waitcnt vmcnt(0)" ::: "memory");
  pbar();

  for (int ks = 0; ks < nsteps; ++ks) {
    const int cur = ks & 1;
    stageK(ks + 1, cur ^ 1);
#pragma unroll
    for (int kk = 0; kk < 2; ++kk) {
      bf16x8 af[MFR], bfv[4];
#pragma unroll
      for (int mf = 0; mf < MFR; ++mf) {
        int row = (wid >> 1) * 32 + mf * 16 + (lane & 15);
        int col = (kk * 64 + ((lane >> 4) << 4)) ^ ((row & 7) << 4);
        af[mf] = *(const bf16x8*)((const char*)sA[cur] + row * 128 + col);
      }
#pragma unroll
      for (int nf = 0; nf < 4; ++nf) {
        int row = (wid & 1) * 64 + nf * 16 + (lane & 15);
        int col = (kk * 64 + ((lane >> 4) << 4)) ^ ((row & 7) << 4);
        bfv[nf] = *(const bf16x8*)((const char*)sB[cur] + row * 128 + col);
      }
#pragma unroll
      for (int mf = 0; mf < MFR; ++mf)
#pragma unroll
        for (int nf = 0; nf < 4; ++nf)
          acc[mf][nf] = __builtin_amdgcn_mfma_f32_16x16x32_bf16(
              af[mf], bfv[nf], acc[mf][nf], 0, 0, 0);
    }
    asm volatile("s_waitcnt vmcnt(0)" ::: "memory");
    pbar();
  }

  const int wr = wid >> 1, wc = wid & 1;
#pragma unroll
  for (int mf = 0; mf < MFR; ++mf) {
#pragma unroll
    for (int j = 0; j < 4; ++j) {
      int row = m0 + wr * 32 + mf * 16 + ((lane >> 4) << 2) + j;
      int b = 0, my = 0, mx = 0;
      if (EP == EP_PM) {
        mx = row & ((1 << p.MXlog) - 1);
        my = (row >> p.MXlog) & ((1 << p.MYlog) - 1);
        b = row >> (p.MXlog + p.MYlog);
      }
#pragma unroll
      for (int nf = 0; nf < 4; ++nf) {
        int col = n0 + wc * 64 + nf * 16 + (lane & 15);
        float v = acc[mf][nf][j];
        if (EP == EP_PM) v += p.bias[col];
        if (RELU) v = v > 0.f ? v : 0.f;
        if (EP == EP_F32) {
          ((float*)p.out)[(size_t)row * p.Nout + col] = v;
        } else {
          int oy = my + 1, ox = mx + 1;
          ((unsigned short*)p.out)[((size_t)(b * p.HPo + oy) * p.WPo + ox) * 128 + col] =
              f2bf(v);
        }
      }
    }
  }
}

// ---------------- 256x256 GEMM (conv3), 2 phases/K-tile, XCD-swizzled ----------------
struct G2 {
  const unsigned short* A;
  const unsigned short* Bt;
  const float* bias;
  unsigned short* out;
  int Klen;
  int WPin, strideBA;
  int Nout;
};

template <int GM>
__global__ __launch_bounds__(512, 2) void gemm256_k(G2 p) {
  __shared__ __align__(16) unsigned short lds[8 * 8192];  // 128 KiB
  const int tid = threadIdx.x, lane = tid & 63, wid = tid >> 6;
  const int wr = wid >> 2, wc = wid & 3;
  // T1 XCD swizzle: nwg = 32*8 = 256, 256%8==0 -> bijective chunked remap
  const int lin = blockIdx.y * gridDim.x + blockIdx.x;
  const int cpx = (gridDim.x * gridDim.y) >> 3;
  const int wg = (lin & 7) * cpx + (lin >> 3);
  const int bx = wg % gridDim.x, by = wg / gridDim.x;
  const int m0 = bx * 256, n0 = by * 256;
  const int sw = ((lane & 7) ^ (lane >> 3)) * 8;
  const int xc0 = ((lane >> 4) ^ (lane & 7)) * 16;
  const int xc1 = (((lane >> 4) | 4) ^ (lane & 7)) * 16;

  int rcA[2][2], rcB[2][2];
#pragma unroll
  for (int h = 0; h < 2; ++h)
#pragma unroll
    for (int i = 0; i < 2; ++i) {
      int m = m0 + h * 128 + wid * 16 + i * 8 + (lane >> 3);
      if (GM == GM_CONV) {
        int mx = m & 31, my = (m >> 5) & 31, b = m >> 10;
        rcA[h][i] = b * p.strideBA + ((2 * my) * p.WPin + 2 * mx) * 128;
      } else {
        rcA[h][i] = m * p.Klen;
      }
      int n = n0 + h * 128 + wid * 16 + i * 8 + (lane >> 3);
      rcB[h][i] = n * p.Klen;
    }

  const int JMAX = p.Klen >> 4;

  auto stage = [&](int j) {
    if (j >= JMAX) return;
    const int T = j >> 2, type = j & 3, slot = j & 7;
    unsigned short* dst = &lds[slot * 8192 + wid * 1024];
    if (type < 2) {
      const int ko = (T << 6) + sw;
      gload_lds16(p.Bt + rcB[type][0] + ko, dst);
      gload_lds16(p.Bt + rcB[type][1] + ko, dst + 512);
    } else {
      int ko;
      if (GM == GM_CONV) {
        const int t = T >> 1;
        ko = ((t >> 2) * p.WPin + (t & 3)) * 128 + ((T & 1) << 6) + sw;
      } else {
        ko = (T << 6) + sw;
      }
      gload_lds16(p.A + rcA[type - 2][0] + ko, dst);
      gload_lds16(p.A + rcA[type - 2][1] + ko, dst + 512);
    }
  };

  f32x4 acc[8][4];
#pragma unroll
  for (int i = 0; i < 8; ++i)
#pragma unroll
    for (int j = 0; j < 4; ++j) acc[i][j] = (f32x4){0.f, 0.f, 0.f, 0.f};

#pragma unroll
  for (int j = 0; j < 6; ++j) stage(j);
  asm volatile("s_waitcnt vmcnt(4)" ::: "memory");
  pbar();

  const int NT = p.Klen >> 6;
  bf16x8 a[4][2], b[4][2];
  for (int t = 0; t < NT; ++t) {
    const int sb = (t & 1) << 2;
    const char* myA = (const char*)&lds[(sb + 2 + wr) * 8192];
    const char* myB = (const char*)&lds[(sb + (wc >> 1)) * 8192];
    const int p4 = t << 2;
#pragma unroll
    for (int mf = 0; mf < 4; ++mf) {
      const int r = mf * 16 + (lane & 15);
      a[mf][0] = *(const bf16x8*)(myA + r * 128 + xc0);
      a[mf][1] = *(const bf16x8*)(myA + r * 128 + xc1);
    }
#pragma unroll
    for (int nf = 0; nf < 4; ++nf) {
      const int c = (wc & 1) * 64 + nf * 16 + (lane & 15);
      b[nf][0] = *(const bf16x8*)(myB + c * 128 + xc0);
      b[nf][1] = *(const bf16x8*)(myB + c * 128 + xc1);
    }
    stage(p4 + 6);
    stage(p4 + 7);
    pbar();
    __builtin_amdgcn_s_setprio(1);
#pragma unroll
    for (int mf = 0; mf < 4; ++mf)
#pragma unroll
      for (int nf = 0; nf < 4; ++nf)
#pragma unroll
        for (int kk = 0; kk < 2; ++kk)
          acc[mf][nf] = __builtin_amdgcn_mfma_f32_16x16x32_bf16(
              a[mf][kk], b[nf][kk], acc[mf][nf], 0, 0, 0);
    __builtin_amdgcn_s_setprio(0);
    pbar();
#pragma unroll
    for (int mf = 0; mf < 4; ++mf) {
      const int r = 64 + mf * 16 + (lane & 15);
      a[mf][0] = *(const bf16x8*)(myA + r * 128 + xc0);
      a[mf][1] = *(const bf16x8*)(myA + r * 128 + xc1);
    }
    stage(p4 + 8);
    stage(p4 + 9);
    pbar();
    __builtin_amdgcn_s_setprio(1);
#pragma unroll
    for (int mf = 0; mf < 4; ++mf)
#pragma unroll
      for (int nf = 0; nf < 4; ++nf)
#pragma unroll
        for (int kk = 0; kk < 2; ++kk)
          acc[mf + 4][nf] = __builtin_amdgcn_mfma_f32_16x16x32_bf16(
              a[mf][kk], b[nf][kk], acc[mf + 4][nf], 0, 0, 0);
    __builtin_amdgcn_s_setprio(0);
    asm volatile("s_waitcnt vmcnt(4)" ::: "memory");
    pbar();
  }

#pragma unroll
  for (int mf = 0; mf < 8; ++mf) {
#pragma unroll
    for (int j = 0; j < 4; ++j) {
      int row = m0 + wr * 128 + mf * 16 + ((lane >> 4) << 2) + j;
#pragma unroll
      for (int nf = 0; nf < 4; ++nf) {
        int col = n0 + wc * 64 + nf * 16 + (lane & 15);
        float v = acc[mf][nf][j] + p.bias[col];
        p.out[(size_t)row * p.Nout + col] = f2bf(v);
      }
    }
  }
}

// ---------------- VQ 8-phase GEMM + argmin + z-norms, XCD-swizzled ----------------
struct GV {
  const unsigned short* A;
  const unsigned short* Bt;
  const float* cnorm;
  float* cval;
  int* cidx;
  float* zn;   // [8192] per-row ||z||^2 (written by by==0)
};

__global__ __launch_bounds__(512, 2) void vq8_k(GV p) {
  __shared__ __align__(16) unsigned short lds[49152];  // 96 KiB
  const int tid = threadIdx.x, lane = tid & 63, wid = tid >> 6;
  const int wr = wid >> 2, wc = wid & 3;
  // T1 XCD swizzle: nwg = 64*4 = 256
  const int lin = blockIdx.y * gridDim.x + blockIdx.x;
  const int cpx = (gridDim.x * gridDim.y) >> 3;
  const int wg = (lin & 7) * cpx + (lin >> 3);
  const int bx = wg % gridDim.x, by = wg / gridDim.x;
  const int m0 = bx * 128, n0 = by * 256;
  const int sw = ((lane & 7) ^ (lane >> 3)) * 8;
  const int xc0 = ((lane >> 4) ^ (lane & 7)) * 16;
  const int xc1 = (((lane >> 4) | 4) ^ (lane & 7)) * 16;
  const int K = 2048;

  int rcA[2];
#pragma unroll
  for (int h = 0; h < 2; ++h)
    rcA[h] = (m0 + h * 64 + wid * 8 + (lane >> 3)) * K;
  int rcB[2][2];
#pragma unroll
  for (int h = 0; h < 2; ++h)
#pragma unroll
    for (int i = 0; i < 2; ++i)
      rcB[h][i] = (n0 + h * 128 + wid * 16 + i * 8 + (lane >> 3)) * K;

  auto stage = [&](int j) {
    if (j >= 128) return;
    const int T = j >> 2, type = j & 3;
    unsigned short* reg = &lds[(T & 1) * 24576];
    const int ko = (T << 6) + sw;
    if (type < 2) {
      gload_lds16(p.A + rcA[type] + ko, reg + type * 4096 + wid * 512);
    } else {
      unsigned short* d = reg + 8192 + (type - 2) * 8192 + wid * 1024;
      gload_lds16(p.Bt + rcB[type - 2][0] + ko, d);
      gload_lds16(p.Bt + rcB[type - 2][1] + ko, d + 512);
    }
  };

  f32x4 acc[4][4];
#pragma unroll
  for (int i = 0; i < 4; ++i)
#pragma unroll
    for (int j = 0; j < 4; ++j) acc[i][j] = (f32x4){0.f, 0.f, 0.f, 0.f};

  float zsum[4] = {0.f, 0.f, 0.f, 0.f};

#pragma unroll
  for (int j = 0; j < 6; ++j) stage(j);
  asm volatile("s_waitcnt vmcnt(2)" ::: "memory");
  pbar();

  bf16x8 a[4][2], b[4][2];
  for (int t = 0; t < 32; ++t) {
    const char* reg = (const char*)&lds[(t & 1) * 24576];
    const char* myA = reg + wr * 8192;
    const char* myB = reg + 16384 + (wc >> 1) * 16384;
    const int p4 = t << 2;
#pragma unroll
    for (int mf = 0; mf < 4; ++mf) {
      const int r = mf * 16 + (lane & 15);
      a[mf][0] = *(const bf16x8*)(myA + r * 128 + xc0);
      a[mf][1] = *(const bf16x8*)(myA + r * 128 + xc1);
    }
    if (wc == 0) {
#pragma unroll
      for (int mf = 0; mf < 4; ++mf)
#pragma unroll
        for (int kk = 0; kk < 2; ++kk)
#pragma unroll
          for (int i = 0; i < 8; ++i) {
            float z = bf2f((unsigned short)a[mf][kk][i]);
            zsum[mf] += z * z;
          }
    }
#pragma unroll
    for (int nf = 0; nf < 4; ++nf) {
      const int c = (wc & 1) * 64 + nf * 16 + (lane & 15);
      b[nf][0] = *(const bf16x8*)(myB + c * 128 + xc0);
      b[nf][1] = *(const bf16x8*)(myB + c * 128 + xc1);
    }
    stage(p4 + 6);
    stage(p4 + 7);
    pbar();
    __builtin_amdgcn_s_setprio(1);
#pragma unroll
    for (int mf = 0; mf < 4; ++mf)
#pragma unroll
      for (int nf = 0; nf < 2; ++nf)
#pragma unroll
        for (int kk = 0; kk < 2; ++kk)
          acc[mf][nf] = __builtin_amdgcn_mfma_f32_16x16x32_bf16(
              a[mf][kk], b[nf][kk], acc[mf][nf], 0, 0, 0);
    __builtin_amdgcn_s_setprio(0);
    pbar();
    stage(p4 + 8);
    stage(p4 + 9);
    pbar();
    __builtin_amdgcn_s_setprio(1);
#pragma unroll
    for (int mf = 0; mf < 4; ++mf)
#pragma unroll
      for (int nf = 2; nf < 4; ++nf)
#pragma unroll
        for (int kk = 0; kk < 2; ++kk)
          acc[mf][nf] = __builtin_amdgcn_mfma_f32_16x16x32_bf16(
              a[mf][kk], b[nf][kk], acc[mf][nf], 0, 0, 0);
    __builtin_amdgcn_s_setprio(0);
    asm volatile("s_waitcnt vmcnt(2)" ::: "memory");
    pbar();
  }

  // z-norm reduce (lanes vary over bits 4-5 = K slices) and write
  if (by == 0 && wc == 0) {
#pragma unroll
    for (int mf = 0; mf < 4; ++mf) {
      zsum[mf] += __shfl_xor(zsum[mf], 16, 64);
      zsum[mf] += __shfl_xor(zsum[mf], 32, 64);
    }
    if (lane < 16) {
#pragma unroll
      for (int mf = 0; mf < 4; ++mf)
        p.zn[m0 + wr * 64 + mf * 16 + lane] = zsum[mf];
    }
  }

  __syncthreads();
  float* sV = (float*)lds;
  int* sI = (int*)(sV + 512);
  float cn[4];
#pragma unroll
  for (int nf = 0; nf < 4; ++nf)
    cn[nf] = p.cnorm[n0 + wc * 64 + nf * 16 + (lane & 15)];
#pragma unroll
  for (int mf = 0; mf < 4; ++mf) {
#pragma unroll
    for (int j = 0; j < 4; ++j) {
      float bv = 3.4e38f;
      int bi = 0x7fffffff;
#pragma unroll
      for (int nf = 0; nf < 4; ++nf) {
        int col = n0 + wc * 64 + nf * 16 + (lane & 15);
        float d = cn[nf] - 2.f * acc[mf][nf][j];
        if (d < bv) { bv = d; bi = col; }
      }
#pragma unroll
      for (int w = 1; w <= 8; w <<= 1) {
        float ov = __shfl_xor(bv, w, 64);
        int oi = __shfl_xor(bi, w, 64);
        if (ov < bv || (ov == bv && oi < bi)) { bv = ov; bi = oi; }
      }
      int lrow = wr * 64 + mf * 16 + ((lane >> 4) << 2) + j;
      if ((lane & 15) == 0) { sV[lrow * 4 + wc] = bv; sI[lrow * 4 + wc] = bi; }
    }
  }
  __syncthreads();
  if (tid < 128) {
    float bv = sV[tid * 4];
    int bi = sI[tid * 4];
#pragma unroll
    for (int c = 1; c < 4; ++c) {
      float v = sV[tid * 4 + c];
      int i2 = sI[tid * 4 + c];
      if (v < bv) { bv = v; bi = i2; }
    }
    p.cval[(size_t)(m0 + tid) * 4 + by] = bv;
    p.cidx[(size_t)(m0 + tid) * 4 + by] = bi;
  }
}

// ---------------- fused final argmin + loss (single block) ----------------
__global__ __launch_bounds__(256) void lossfin_k(const float* __restrict__ zn,
                                                 const float* __restrict__ cval,
                                                 const int* __restrict__ cidx,
                                                 int* __restrict__ idx,
                                                 float* __restrict__ out) {
  int tid = threadIdx.x;
  float s = 0.f;
  for (int m = tid; m < 8192; m += 256) {
    float bv = cval[(size_t)m * 4];
    int bi = cidx[(size_t)m * 4];
#pragma unroll
    for (int j = 1; j < 4; ++j) {
      float v = cval[(size_t)m * 4 + j];
      int i2 = cidx[(size_t)m * 4 + j];
      if (v < bv) { bv = v; bi = i2; }
    }
    idx[m] = bi;
    s += zn[m] + bv;
  }
  __shared__ float red[4];
  for (int off = 32; off > 0; off >>= 1) s += __shfl_down(s, off, 64);
  if ((tid & 63) == 0) red[tid >> 6] = s;
  __syncthreads();
  if (tid == 0) out[0] = 1.25f * (red[0] + red[1] + red[2] + red[3]) / 16777216.f;
}

// ---------------- deconv1 via codebook factorization ----------------
__global__ __launch_bounds__(256) void dc1gather_k(const float* __restrict__ V,
                                                   const int* __restrict__ idx,
                                                   const float* __restrict__ bias,
                                                   unsigned short* __restrict__ h3) {
  int b = blockIdx.x >> 6;
  int oy = blockIdx.x & 63;
  int co = threadIdx.x & 127;
  int xh = threadIdx.x >> 7;
  __shared__ int sIdx[2][32];
  int iyA = (oy + 1) >> 1, kyA = (oy + 1) & 1;
  int iyB = iyA - 1, kyB = kyA + 2;
  if (threadIdx.x < 64) {
    int which = threadIdx.x >> 5;
    int ix = threadIdx.x & 31;
    int iy = which ? iyB : iyA;
    sIdx[which][ix] = (iy >= 0 && iy < 32) ? idx[(b << 10) + (iy << 5) + ix] : -1;
  }
  __syncthreads();
  float bb = bias[co];
  for (int xi = 0; xi < 32; ++xi) {
    int ox = xh * 32 + xi;
    int ixA = (ox + 1) >> 1, kxA = (ox + 1) & 1;
    int ixB = ixA - 1, kxB = kxA + 2;
    float s = bb;
    int kAA = (ixA < 32) ? sIdx[0][ixA] : -1;
    if (kAA >= 0) s += V[((size_t)(kAA * 16 + kyA * 4 + kxA)) * 128 + co];
    int kAB = (ixB >= 0) ? sIdx[0][ixB] : -1;
    if (kAB >= 0) s += V[((size_t)(kAB * 16 + kyA * 4 + kxB)) * 128 + co];
    int kBA = (ixA < 32) ? sIdx[1][ixA] : -1;
    if (kBA >= 0) s += V[((size_t)(kBA * 16 + kyB * 4 + kxA)) * 128 + co];
    int kBB = (ixB >= 0) ? sIdx[1][ixB] : -1;
    if (kBB >= 0) s += V[((size_t)(kBB * 16 + kyB * 4 + kxB)) * 128 + co];
    s = s > 0.f ? s : 0.f;
    h3[((size_t)(b * 66 + oy + 1) * 66 + (ox + 1)) * 128 + co] = f2bf(s);
  }
}

// ---------------- deconv3 (128->1) + sigmoid, LDS-row-staged ----------------
__global__ __launch_bounds__(256) void deconv3_k(const unsigned short* __restrict__ h4,
                                                 const float* __restrict__ wd,
                                                 const float* __restrict__ b3,
                                                 float* __restrict__ out) {
  __shared__ __align__(16) char sRow[2 * 130 * 272];
  __shared__ float sW[2048];
  const int tid = threadIdx.x;
  const int b = blockIdx.x >> 8, oy = blockIdx.x & 255;
  const int py = oy & 1, uy = oy >> 1;
  const int g0 = uy + py;
  for (int i = tid; i < 2048; i += 256) sW[i] = wd[i];
  for (int g = tid; g < 4160; g += 256) {
    int r = (g >= 2080) ? 1 : 0;
    int gg = g - r * 2080;
    int px = gg >> 4, k = gg & 15;
    const bf16x8* src =
        (const bf16x8*)(h4 + (((size_t)(b * 130 + g0 + r) * 130 + px) << 7) + k * 8);
    *(bf16x8*)(sRow + r * 35360 + px * 272 + k * 16) = *src;
  }
  __syncthreads();
  const int ox = tid;
  const int pxp = ox & 1, ux = ox >> 1;
  const int z = py * 2 + pxp;
  float s = b3[0];
#pragma unroll
  for (int ty = 0; ty < 2; ++ty) {
#pragma unroll
    for (int tx = 0; tx < 2; ++tx) {
      int ixp = ux + 1 + pxp - tx;
      const char* base = sRow + (1 - ty) * 35360 + ixp * 272;
      const float* wp = &sW[z * 512 + (ty * 2 + tx) * 128];
#pragma unroll
      for (int k = 0; k < 16; ++k) {
        bf16x8 v = *(const bf16x8*)(base + k * 16);
#pragma unroll
        for (int i = 0; i < 8; ++i)
          s += bf2f((unsigned short)v[i]) * wp[k * 8 + i];
      }
    }
  }
  out[(size_t)blockIdx.x * 256 + ox] = 1.f / (1.f + __expf(-s));
}

// ---------------- launch ----------------
extern "C" void kernel_launch(void* const* d_in, const int* in_sizes, int n_in,
                              void* d_out, int out_size, void* d_ws, size_t ws_size,
                              hipStream_t stream) {
  const float* x = (const float*)d_in[0];
  const float* ew1 = (const float*)d_in[1];
  const float* eb1 = (const float*)d_in[2];
  const float* ew2 = (const float*)d_in[3];
  const float* eb2 = (const float*)d_in[4];
  const float* ew3 = (const float*)d_in[5];
  const float* eb3 = (const float*)d_in[6];
  const float* cb = (const float*)d_in[7];
  const float* dw1 = (const float*)d_in[8];
  const float* db1 = (const float*)d_in[9];
  const float* dw2 = (const float*)d_in[10];
  const float* db2 = (const float*)d_in[11];
  const float* dw3 = (const float*)d_in[12];
  const float* db3 = (const float*)d_in[13];
  float* out = (float*)d_out;

  char* w = (char*)d_ws;
  size_t off = 0;
  auto alloc = [&](size_t bytes) {
    char* p = w + off;
    off = (off + bytes + 255) & ~(size_t)255;
    return p;
  };
  const size_t sz_h1 = 8ull * 130 * 130 * 128 * 2;  // 34.6 MB
  const size_t sz_h2 = 8ull * 66 * 66 * 128 * 2;    // 8.9 MB
  const size_t sz_zf = 8192ull * 2048 * 2;          // 33.6 MB
  unsigned short* h1 = (unsigned short*)alloc(sz_h1);
  unsigned short* h2 = (unsigned short*)alloc(sz_h2);
  unsigned short* zf = (unsigned short*)alloc(sz_zf);
  unsigned short* cbb = (unsigned short*)alloc(1024ull * 2048 * 2);
  float* cnorm = (float*)alloc(1024 * 4);
  int* idx = (int*)alloc(8192 * 4);
  unsigned short* h4 = (unsigned short*)alloc(sz_h1);
  unsigned short* bt2 = (unsigned short*)alloc(128ull * 2048 * 2);
  unsigned short* bt3 = (unsigned short*)alloc(2048ull * 2048 * 2);
  unsigned short* btw1 = (unsigned short*)alloc(2048ull * 2048 * 2);
  unsigned short* btd2 = (unsigned short*)alloc(4ull * 128 * 512 * 2);
  float* V = (float*)alloc(1024ull * 16 * 128 * 4);  // 8.4 MB
  float* wd3 = (float*)alloc(2048 * 4);
  unsigned short* h3 = (unsigned short*)alloc(sz_h2);
  float* cval = (float*)alloc(8192ull * 4 * 4);
  int* cidx = (int*)alloc(8192ull * 4 * 4);
  float* zn = (float*)alloc(8192 * 4);

  halo_k<<<6208, 256, 0, stream>>>(h1, h2, h3, h4);
  packT_k<<<4352, 256, 0, stream>>>(ew2, ew3, dw1, dw2, bt2, bt3, btw1, btd2);
  pack_cb<<<1025, 256, 0, stream>>>(cb, dw3, cbb, cnorm, wd3);
  conv1_k<<<1024, 256, 0, stream>>>(x, ew1, eb1, h1);

  // V = codebook . w1-factor: M=1024, N=2048, K=2048 (2-phase pipelined)
  GP pcw = {cbb, btw1, nullptr, V, 2048, 11, 0, 0, 0, 0, 0, 0,
            2048, 2048, 0, 0, 0, 0};
  gemmp_k<GM_FLAT, EP_F32, 0><<<dim3(16, 16, 1), 256, 0, stream>>>(pcw);

  // conv2: M=32768(64x64), N=128, K=2048 (2-phase pipelined)
  GP p2 = {h1, bt2, eb2, h2, 2048, 7, 6, 6, 130, 130 * 130 * 128, 66, 66,
           128, 2048, 0, 0, 0, 0};
  gemmp_k<GM_CONV, EP_PM, 1><<<dim3(512, 1, 1), 256, 0, stream>>>(p2);

  // conv3 (2-phase 256^2, XCD-swizzled): M=8192, N=2048, K=2048 -> z_flat
  G2 g3 = {h2, bt3, eb3, zf, 2048, 66, 66 * 66 * 128, 2048};
  gemm256_k<GM_CONV><<<dim3(32, 8, 1), 512, 0, stream>>>(g3);

  // VQ (8-phase 128x256, XCD-swizzled) + fused argmin + z-norms
  GV pv = {zf, cbb, cnorm, cval, cidx, zn};
  vq8_k<<<dim3(64, 4, 1), 512, 0, stream>>>(pv);

  // final argmin + loss in one dispatch
  lossfin_k<<<1, 256, 0, stream>>>(zn, cval, cidx, idx, out + 524288);

  // deconv1 = gather from V by idx (+bias, ReLU) -> h3 padded
  dc1gather_k<<<512, 256, 0, stream>>>(V, idx, db1, h3);

  // deconv2: per class M=32768(64x64), N=128, K=512, BM=128 (high occupancy)
  GP pd2 = {h3, btd2, db2, h4, 512, 7, 6, 6, 66, 66 * 66 * 128, 130, 130,
            128, 512, 128 * 512, 2, 0, 0};
  gemm_k<128, GM_DECONV, EP_PM, 1><<<dim3(256, 1, 4), 256, 0, stream>>>(pd2);

  deconv3_k<<<2048, 256, 0, stream>>>(h4, wd3, db3, out);
  (void)in_sizes; (void)n_in; (void)out_size; (void)ws_size;
}

// Round 17
// 352.214 us; speedup vs baseline: 1.0432x; 1.0432x over previous
//
#include <hip/hip_runtime.h>

typedef __attribute__((ext_vector_type(8))) short bf16x8;
typedef __attribute__((ext_vector_type(4))) float f32x4;

__device__ __forceinline__ unsigned short f2bf(float f) {
  unsigned u = __float_as_uint(f);
  u += 0x7fff + ((u >> 16) & 1);
  return (unsigned short)(u >> 16);
}
__device__ __forceinline__ float bf2f(unsigned short h) {
  return __uint_as_float(((unsigned)h) << 16);
}

__device__ __forceinline__ void gload_lds16(const void* g, void* l) {
  __builtin_amdgcn_global_load_lds((const __attribute__((address_space(1))) void*)g,
                                   (__attribute__((address_space(3))) void*)l, 16, 0, 0);
}

// raw s_barrier + compiler memory fence (no sched_barrier pinning — m141)
__device__ __forceinline__ void pbar() {
  asm volatile("" ::: "memory");
  __builtin_amdgcn_s_barrier();
  asm volatile("" ::: "memory");
}

// ---------------- halo zeroing ----------------
__global__ __launch_bounds__(256) void halo_k(unsigned short* __restrict__ h1,
                                              unsigned short* __restrict__ h2,
                                              unsigned short* __restrict__ h3,
                                              unsigned short* __restrict__ h4) {
  int pid = blockIdx.x * 2 + (threadIdx.x >> 7);  // [0, 12416)
  int co = threadIdx.x & 127;
  unsigned short* buf;
  int b, e, SP;
  if (pid < 8256) {
    buf = (pid < 4128) ? h1 : h4;
    int rel = (pid < 4128) ? pid : pid - 4128;
    b = rel / 516; e = rel % 516; SP = 130;
    int y, x;
    if (e < 130) { y = 0; x = e; }
    else if (e < 260) { y = 129; x = e - 130; }
    else if (e < 388) { y = 1 + (e - 260); x = 0; }
    else { y = 1 + (e - 388); x = 129; }
    buf[(((size_t)(b * SP + y)) * SP + x) * 128 + co] = 0;
  } else {
    buf = (pid < 10336) ? h2 : h3;
    int rel = pid - ((pid < 10336) ? 8256 : 10336);
    b = rel / 260; e = rel % 260; SP = 66;
    int y, x;
    if (e < 66) { y = 0; x = e; }
    else if (e < 132) { y = 65; x = e - 66; }
    else if (e < 196) { y = 1 + (e - 132); x = 0; }
    else { y = 1 + (e - 196); x = 65; }
    buf[(((size_t)(b * SP + y)) * SP + x) * 128 + co] = 0;
  }
}

// ---------------- coalesced transpose weight packing ----------------
__global__ __launch_bounds__(256) void packT_k(
    const float* __restrict__ ew2, const float* __restrict__ ew3,
    const float* __restrict__ dw1, const float* __restrict__ dw2,
    unsigned short* __restrict__ bt2, unsigned short* __restrict__ bt3,
    unsigned short* __restrict__ btw1, unsigned short* __restrict__ btd2) {
  __shared__ float sT[128 * 17 + 16];
  const int tid = threadIdx.x;
  const int blk = blockIdx.x;
  if (blk < 2048) {
    const int co = blk;
    const float* src = ew3 + (size_t)co * 2048;
    const int ci = tid >> 1, k0 = (tid & 1) * 8;
#pragma unroll
    for (int e = 0; e < 8; ++e) sT[ci * 17 + k0 + e] = src[tid * 8 + e];
    __syncthreads();
    const int kko = tid >> 4, ci0 = (tid & 15) * 8;
    unsigned short v[8];
#pragma unroll
    for (int e = 0; e < 8; ++e) v[e] = f2bf(sT[(ci0 + e) * 17 + kko]);
    *(bf16x8*)(bt3 + (size_t)co * 2048 + tid * 8) = *(bf16x8*)v;
  } else if (blk < 4096) {
    const int r = blk - 2048;
    const int co = r & 127, c0 = (r >> 7) << 7;
    const int ci = tid >> 1, t0 = (tid & 1) * 8;
    const float* src = dw1 + ((size_t)(c0 + ci) * 128 + co) * 16 + t0;
#pragma unroll
    for (int e = 0; e < 8; ++e) sT[ci * 17 + t0 + e] = src[e];
    __syncthreads();
    const int t = tid >> 4, ci0 = (tid & 15) * 8;
    unsigned short v[8];
#pragma unroll
    for (int e = 0; e < 8; ++e) v[e] = f2bf(sT[(ci0 + e) * 17 + t]);
    *(bf16x8*)(btw1 + (size_t)(t * 128 + co) * 2048 + c0 + ci0) = *(bf16x8*)v;
  } else if (blk < 4224) {
    const int co = blk - 4096;
    const float* src = ew2 + (size_t)co * 2048;
    const int ci = tid >> 1, k0 = (tid & 1) * 8;
#pragma unroll
    for (int e = 0; e < 8; ++e) sT[ci * 17 + k0 + e] = src[tid * 8 + e];
    __syncthreads();
    const int kko = tid >> 4, ci0 = (tid & 15) * 8;
    unsigned short v[8];
#pragma unroll
    for (int e = 0; e < 8; ++e) v[e] = f2bf(sT[(ci0 + e) * 17 + kko]);
    *(bf16x8*)(bt2 + (size_t)co * 2048 + tid * 8) = *(bf16x8*)v;
  } else {
    const int co = blk - 4224;
    const int ci = tid >> 1, t0 = (tid & 1) * 8;
    const float* src = dw2 + ((size_t)ci * 128 + co) * 16 + t0;
#pragma unroll
    for (int e = 0; e < 8; ++e) sT[ci * 17 + t0 + e] = src[e];
    __syncthreads();
    const int zt = tid >> 4, ci0 = (tid & 15) * 8;
    const int z = zt >> 2, tp = zt & 3;
    const int py = z >> 1, px = z & 1, ty = tp >> 1, tx = tp & 1;
    const int kk = (2 * ty + 1 - py) * 4 + (2 * tx + 1 - px);
    unsigned short v[8];
#pragma unroll
    for (int e = 0; e < 8; ++e) v[e] = f2bf(sT[(ci0 + e) * 17 + kk]);
    *(bf16x8*)(btd2 + ((size_t)(z * 128 + co) * 4 + tp) * 128 + ci0) = *(bf16x8*)v;
  }
}

// ---------------- codebook pack (+wd3 in last block) ----------------
__global__ __launch_bounds__(256) void pack_cb(const float* __restrict__ cb,
                                               const float* __restrict__ dw3,
                                               unsigned short* __restrict__ cbb,
                                               float* __restrict__ cnorm,
                                               float* __restrict__ wd3) {
  int r = blockIdx.x;
  if (r == 1024) {
#pragma unroll
    for (int e = 0; e < 8; ++e) {
      int j = threadIdx.x * 8 + e;  // [0,2048)
      int ci = j & 127, t = (j >> 7) & 3, z = j >> 9;
      int py = z >> 1, px = z & 1, ty = t >> 1, tx = t & 1;
      int ky = 2 * ty + 1 - py, kx = 2 * tx + 1 - px;
      wd3[j] = dw3[ci * 16 + ky * 4 + kx];
    }
    return;
  }
  const float* src = cb + (size_t)r * 2048;
  float s = 0.f;
  for (int i = threadIdx.x; i < 2048; i += 256) {
    float v = src[i];
    cbb[(size_t)r * 2048 + i] = f2bf(v);
    s += v * v;
  }
  __shared__ float red[4];
  for (int off = 32; off > 0; off >>= 1) s += __shfl_down(s, off, 64);
  int lane = threadIdx.x & 63, wid = threadIdx.x >> 6;
  if (lane == 0) red[wid] = s;
  __syncthreads();
  if (threadIdx.x == 0) cnorm[r] = red[0] + red[1] + red[2] + red[3];
}

// ---------------- conv1 (3->128, direct) ----------------
__global__ __launch_bounds__(256) void conv1_k(const float* __restrict__ x,
                                               const float* __restrict__ w1,
                                               const float* __restrict__ b1,
                                               unsigned short* __restrict__ h1) {
  __shared__ float sIn[3][4][258];
  int b = blockIdx.x >> 7, y = blockIdx.x & 127;
  for (int i = threadIdx.x; i < 3 * 4 * 258; i += 256) {
    int c = i / (4 * 258);
    int rr = (i / 258) % 4;
    int col = i % 258;
    int iy = 2 * y - 1 + rr;
    int ix = col - 1;
    float v = (iy >= 0 && iy < 256 && ix >= 0 && ix < 256)
                  ? x[((size_t)(b * 3 + c) * 256 + iy) * 256 + ix] : 0.f;
    sIn[c][rr][col] = v;
  }
  __syncthreads();
  int co = threadIdx.x & 127, xh = threadIdx.x >> 7;
  float w[3][4][4];
#pragma unroll
  for (int c = 0; c < 3; ++c)
#pragma unroll
    for (int ky = 0; ky < 4; ++ky)
#pragma unroll
      for (int kx = 0; kx < 4; ++kx)
        w[c][ky][kx] = w1[(((size_t)co * 3 + c) * 4 + ky) * 4 + kx];
  float bb = b1[co];
  for (int xi = 0; xi < 64; ++xi) {
    int xx = xh * 64 + xi;
    float acc = bb;
#pragma unroll
    for (int c = 0; c < 3; ++c)
#pragma unroll
      for (int ky = 0; ky < 4; ++ky)
#pragma unroll
        for (int kx = 0; kx < 4; ++kx)
          acc += sIn[c][ky][2 * xx + kx] * w[c][ky][kx];
    acc = acc > 0.f ? acc : 0.f;
    h1[((size_t)(b * 130 + y + 1) * 130 + (xx + 1)) * 128 + co] = f2bf(acc);
  }
}

// ---------------- generic implicit-GEMM defs ----------------
#define GM_CONV 0
#define GM_DECONV 1
#define GM_FLAT 2
#define EP_PM 0
#define EP_FLATBF 1
#define EP_F32 2

struct GP {
  const unsigned short* A;
  const unsigned short* Bt;
  const float* bias;
  void* out;
  int Klen, Clog;
  int MXlog, MYlog;
  int WPin, strideBA;
  int HPo, WPo;
  int Nout;
  int BrowStride;
  int BclassStride;
  int classLog;
  int TPC;
  int outZ;
};

// ---------------- 2-barrier GEMM (deconv2) ----------------
template <int BM, int GM, int EP, int RELU>
__global__ __launch_bounds__(256) void gemm_k(GP p) {
  constexpr int MFR = BM / 32;
  constexpr int CA = BM / 32;
  const int tid = threadIdx.x;
  const int lane = tid & 63;
  const int wid = tid >> 6;
  const int m0 = blockIdx.x * BM;
  const int n0 = blockIdx.y * 128;
  const int zAll = blockIdx.z;
  const int zc = zAll & ((1 << p.classLog) - 1);
  const int chunk = zAll >> p.classLog;
  const int py = zc >> 1, px = zc & 1;

  __shared__ __align__(16) unsigned short sA[BM * 64];
  __shared__ __align__(16) unsigned short sB[128 * 64];

  const unsigned short* Bt = p.Bt + (size_t)zc * p.BclassStride;
  const int C = 1 << p.Clog;
  const int tb = chunk * p.TPC;
  const int chunkOff = tb << p.Clog;
  const int sw = ((lane & 7) ^ (lane >> 3)) * 8;

  int rcA[CA];
#pragma unroll
  for (int i = 0; i < CA; ++i) {
    int r = (wid * CA + i) * 8 + (lane >> 3);
    int m = m0 + r;
    if (GM == GM_FLAT) {
      rcA[i] = m * p.Klen;
    } else {
      int mx = m & ((1 << p.MXlog) - 1);
      int my = (m >> p.MXlog) & ((1 << p.MYlog) - 1);
      int b = m >> (p.MXlog + p.MYlog);
      if (GM == GM_CONV)
        rcA[i] = b * p.strideBA + ((2 * my) * p.WPin + 2 * mx) * C;
      else
        rcA[i] = b * p.strideBA + ((my + 1) * p.WPin + (mx + 1)) * C;
    }
  }
  int rcB[4];
#pragma unroll
  for (int i = 0; i < 4; ++i) {
    int r = (wid * 4 + i) * 8 + (lane >> 3);
    rcB[i] = (n0 + r) * p.BrowStride;
  }

  f32x4 acc[MFR][4];
#pragma unroll
  for (int a = 0; a < MFR; ++a)
#pragma unroll
    for (int b = 0; b < 4; ++b) acc[a][b] = (f32x4){0.f, 0.f, 0.f, 0.f};

  const int nsteps = p.Klen >> 6;
  for (int ks = 0; ks < nsteps; ++ks) {
    const int k0 = ks << 6;
    int tap = 0;
    if (GM == GM_CONV) {
      int t = tb + (k0 >> p.Clog);
      tap = ((t >> 2) * p.WPin + (t & 3)) * C;
    } else if (GM == GM_DECONV) {
      int t = tb + (k0 >> p.Clog);
      int ty = t >> 1, tx = t & 1;
      tap = ((py - ty) * p.WPin + (px - tx)) * C;
    }
    const int ci0 = k0 & (C - 1);
    const int aoff = tap + ci0 + sw;
#pragma unroll
    for (int i = 0; i < CA; ++i)
      gload_lds16(p.A + rcA[i] + aoff, &sA[(wid * CA + i) * 512]);
#pragma unroll
    for (int i = 0; i < 4; ++i)
      gload_lds16(Bt + rcB[i] + chunkOff + k0 + sw, &sB[(wid * 4 + i) * 512]);
    __syncthreads();

#pragma unroll
    for (int kk = 0; kk < 2; ++kk) {
      bf16x8 af[MFR], bfv[4];
#pragma unroll
      for (int mf = 0; mf < MFR; ++mf) {
        int row = (wid >> 1) * (BM / 2) + mf * 16 + (lane & 15);
        int col = (kk * 64 + ((lane >> 4) << 4)) ^ ((row & 7) << 4);
        af[mf] = *(const bf16x8*)((const char*)sA + row * 128 + col);
      }
#pragma unroll
      for (int nf = 0; nf < 4; ++nf) {
        int row = (wid & 1) * 64 + nf * 16 + (lane & 15);
        int col = (kk * 64 + ((lane >> 4) << 4)) ^ ((row & 7) << 4);
        bfv[nf] = *(const bf16x8*)((const char*)sB + row * 128 + col);
      }
#pragma unroll
      for (int mf = 0; mf < MFR; ++mf)
#pragma unroll
        for (int nf = 0; nf < 4; ++nf)
          acc[mf][nf] = __builtin_amdgcn_mfma_f32_16x16x32_bf16(
              af[mf], bfv[nf], acc[mf][nf], 0, 0, 0);
    }
    __syncthreads();
  }

  const int wr = wid >> 1, wc = wid & 1;
#pragma unroll
  for (int mf = 0; mf < MFR; ++mf) {
#pragma unroll
    for (int j = 0; j < 4; ++j) {
      int row = m0 + wr * (BM / 2) + mf * 16 + ((lane >> 4) << 2) + j;
      int b = 0, my = 0, mx = 0;
      if (EP == EP_PM) {
        mx = row & ((1 << p.MXlog) - 1);
        my = (row >> p.MXlog) & ((1 << p.MYlog) - 1);
        b = row >> (p.MXlog + p.MYlog);
      }
#pragma unroll
      for (int nf = 0; nf < 4; ++nf) {
        int col = n0 + wc * 64 + nf * 16 + (lane & 15);
        float v = acc[mf][nf][j];
        if (EP == EP_PM || EP == EP_FLATBF) v += p.bias[col];
        if (RELU) v = v > 0.f ? v : 0.f;
        if (EP == EP_F32) {
          ((float*)p.out)[(size_t)row * p.Nout + col] = v;
        } else if (EP == EP_FLATBF) {
          ((unsigned short*)p.out)[(size_t)row * p.Nout + col] = f2bf(v);
        } else {
          int oy, ox;
          if (GM == GM_DECONV) {
            oy = 2 * my + py + 1;
            ox = 2 * mx + px + 1;
          } else {
            oy = my + 1;
            ox = mx + 1;
          }
          ((unsigned short*)p.out)[((size_t)(b * p.HPo + oy) * p.WPo + ox) * 128 + col] =
              f2bf(v);
        }
      }
    }
  }
}

// ---------------- 2-phase double-buffered BM=64 GEMM (conv2, V) ----------------
template <int GM, int EP, int RELU>
__global__ __launch_bounds__(256) void gemmp_k(GP p) {
  constexpr int BM = 64;
  constexpr int MFR = 2;
  constexpr int CA = 2;
  const int tid = threadIdx.x;
  const int lane = tid & 63;
  const int wid = tid >> 6;
  const int m0 = blockIdx.x * BM;
  const int n0 = blockIdx.y * 128;

  __shared__ __align__(16) unsigned short sA[2][BM * 64];
  __shared__ __align__(16) unsigned short sB[2][128 * 64];

  const unsigned short* Bt = p.Bt;
  const int C = 1 << p.Clog;
  const int sw = ((lane & 7) ^ (lane >> 3)) * 8;

  int rcA[CA];
#pragma unroll
  for (int i = 0; i < CA; ++i) {
    int r = (wid * CA + i) * 8 + (lane >> 3);
    int m = m0 + r;
    if (GM == GM_FLAT) {
      rcA[i] = m * p.Klen;
    } else {
      int mx = m & ((1 << p.MXlog) - 1);
      int my = (m >> p.MXlog) & ((1 << p.MYlog) - 1);
      int b = m >> (p.MXlog + p.MYlog);
      rcA[i] = b * p.strideBA + ((2 * my) * p.WPin + 2 * mx) * C;
    }
  }
  int rcB[4];
#pragma unroll
  for (int i = 0; i < 4; ++i) {
    int r = (wid * 4 + i) * 8 + (lane >> 3);
    rcB[i] = (n0 + r) * p.BrowStride;
  }

  const int nsteps = p.Klen >> 6;

  auto stageK = [&](int ks, int bs) {
    if (ks >= nsteps) return;
    const int k0 = ks << 6;
    int tap = 0;
    if (GM == GM_CONV) {
      int t = k0 >> p.Clog;
      tap = ((t >> 2) * p.WPin + (t & 3)) * C;
    }
    const int aoff = tap + (k0 & (C - 1)) + sw;
#pragma unroll
    for (int i = 0; i < CA; ++i)
      gload_lds16(p.A + rcA[i] + aoff, &sA[bs][(wid * CA + i) * 512]);
#pragma unroll
    for (int i = 0; i < 4; ++i)
      gload_lds16(Bt + rcB[i] + k0 + sw, &sB[bs][(wid * 4 + i) * 512]);
  };

  f32x4 acc[MFR][4];
#pragma unroll
  for (int a = 0; a < MFR; ++a)
#pragma unroll
    for (int b = 0; b < 4; ++b) acc[a][b] = (f32x4){0.f, 0.f, 0.f, 0.f};

  stageK(0, 0);
  asm volatile("s_waitcnt vmcnt(0)" ::: "memory");
  pbar();

  for (int ks = 0; ks < nsteps; ++ks) {
    const int cur = ks & 1;
    stageK(ks + 1, cur ^ 1);
#pragma unroll
    for (int kk = 0; kk < 2; ++kk) {
      bf16x8 af[MFR], bfv[4];
#pragma unroll
      for (int mf = 0; mf < MFR; ++mf) {
        int row = (wid >> 1) * 32 + mf * 16 + (lane & 15);
        int col = (kk * 64 + ((lane >> 4) << 4)) ^ ((row & 7) << 4);
        af[mf] = *(const bf16x8*)((const char*)sA[cur] + row * 128 + col);
      }
#pragma unroll
      for (int nf = 0; nf < 4; ++nf) {
        int row = (wid & 1) * 64 + nf * 16 + (lane & 15);
        int col = (kk * 64 + ((lane >> 4) << 4)) ^ ((row & 7) << 4);
        bfv[nf] = *(const bf16x8*)((const char*)sB[cur] + row * 128 + col);
      }
#pragma unroll
      for (int mf = 0; mf < MFR; ++mf)
#pragma unroll
        for (int nf = 0; nf < 4; ++nf)
          acc[mf][nf] = __builtin_amdgcn_mfma_f32_16x16x32_bf16(
              af[mf], bfv[nf], acc[mf][nf], 0, 0, 0);
    }
    asm volatile("s_waitcnt vmcnt(0)" ::: "memory");
    pbar();
  }

  const int wr = wid >> 1, wc = wid & 1;
#pragma unroll
  for (int mf = 0; mf < MFR; ++mf) {
#pragma unroll
    for (int j = 0; j < 4; ++j) {
      int row = m0 + wr * 32 + mf * 16 + ((lane >> 4) << 2) + j;
      int b = 0, my = 0, mx = 0;
      if (EP == EP_PM) {
        mx = row & ((1 << p.MXlog) - 1);
        my = (row >> p.MXlog) & ((1 << p.MYlog) - 1);
        b = row >> (p.MXlog + p.MYlog);
      }
#pragma unroll
      for (int nf = 0; nf < 4; ++nf) {
        int col = n0 + wc * 64 + nf * 16 + (lane & 15);
        float v = acc[mf][nf][j];
        if (EP == EP_PM) v += p.bias[col];
        if (RELU) v = v > 0.f ? v : 0.f;
        if (EP == EP_F32) {
          ((float*)p.out)[(size_t)row * p.Nout + col] = v;
        } else {
          int oy = my + 1, ox = mx + 1;
          ((unsigned short*)p.out)[((size_t)(b * p.HPo + oy) * p.WPo + ox) * 128 + col] =
              f2bf(v);
        }
      }
    }
  }
}

// ---------------- 256x256 GEMM (conv3), 2 phases/K-tile x 32 MFMA ----------------
struct G2 {
  const unsigned short* A;
  const unsigned short* Bt;
  const float* bias;
  unsigned short* out;
  int Klen;
  int WPin, strideBA;
  int Nout;
};

template <int GM>
__global__ __launch_bounds__(512, 2) void gemm256_k(G2 p) {
  __shared__ __align__(16) unsigned short lds[8 * 8192];  // 128 KiB
  const int tid = threadIdx.x, lane = tid & 63, wid = tid >> 6;
  const int wr = wid >> 2, wc = wid & 3;
  const int m0 = blockIdx.x * 256, n0 = blockIdx.y * 256;
  const int sw = ((lane & 7) ^ (lane >> 3)) * 8;
  const int xc0 = ((lane >> 4) ^ (lane & 7)) * 16;
  const int xc1 = (((lane >> 4) | 4) ^ (lane & 7)) * 16;

  int rcA[2][2], rcB[2][2];
#pragma unroll
  for (int h = 0; h < 2; ++h)
#pragma unroll
    for (int i = 0; i < 2; ++i) {
      int m = m0 + h * 128 + wid * 16 + i * 8 + (lane >> 3);
      if (GM == GM_CONV) {
        int mx = m & 31, my = (m >> 5) & 31, b = m >> 10;
        rcA[h][i] = b * p.strideBA + ((2 * my) * p.WPin + 2 * mx) * 128;
      } else {
        rcA[h][i] = m * p.Klen;
      }
      int n = n0 + h * 128 + wid * 16 + i * 8 + (lane >> 3);
      rcB[h][i] = n * p.Klen;
    }

  const int JMAX = p.Klen >> 4;

  auto stage = [&](int j) {
    if (j >= JMAX) return;
    const int T = j >> 2, type = j & 3, slot = j & 7;
    unsigned short* dst = &lds[slot * 8192 + wid * 1024];
    if (type < 2) {
      const int ko = (T << 6) + sw;
      gload_lds16(p.Bt + rcB[type][0] + ko, dst);
      gload_lds16(p.Bt + rcB[type][1] + ko, dst + 512);
    } else {
      int ko;
      if (GM == GM_CONV) {
        const int t = T >> 1;
        ko = ((t >> 2) * p.WPin + (t & 3)) * 128 + ((T & 1) << 6) + sw;
      } else {
        ko = (T << 6) + sw;
      }
      gload_lds16(p.A + rcA[type - 2][0] + ko, dst);
      gload_lds16(p.A + rcA[type - 2][1] + ko, dst + 512);
    }
  };

  f32x4 acc[8][4];
#pragma unroll
  for (int i = 0; i < 8; ++i)
#pragma unroll
    for (int j = 0; j < 4; ++j) acc[i][j] = (f32x4){0.f, 0.f, 0.f, 0.f};

#pragma unroll
  for (int j = 0; j < 6; ++j) stage(j);
  asm volatile("s_waitcnt vmcnt(4)" ::: "memory");
  pbar();

  const int NT = p.Klen >> 6;
  bf16x8 a[4][2], b[4][2];
  for (int t = 0; t < NT; ++t) {
    const int sb = (t & 1) << 2;
    const char* myA = (const char*)&lds[(sb + 2 + wr) * 8192];
    const char* myB = (const char*)&lds[(sb + (wc >> 1)) * 8192];
    const int p4 = t << 2;
#pragma unroll
    for (int mf = 0; mf < 4; ++mf) {
      const int r = mf * 16 + (lane & 15);
      a[mf][0] = *(const bf16x8*)(myA + r * 128 + xc0);
      a[mf][1] = *(const bf16x8*)(myA + r * 128 + xc1);
    }
#pragma unroll
    for (int nf = 0; nf < 4; ++nf) {
      const int c = (wc & 1) * 64 + nf * 16 + (lane & 15);
      b[nf][0] = *(const bf16x8*)(myB + c * 128 + xc0);
      b[nf][1] = *(const bf16x8*)(myB + c * 128 + xc1);
    }
    stage(p4 + 6);
    stage(p4 + 7);
    pbar();
    __builtin_amdgcn_s_setprio(1);
#pragma unroll
    for (int mf = 0; mf < 4; ++mf)
#pragma unroll
      for (int nf = 0; nf < 4; ++nf)
#pragma unroll
        for (int kk = 0; kk < 2; ++kk)
          acc[mf][nf] = __builtin_amdgcn_mfma_f32_16x16x32_bf16(
              a[mf][kk], b[nf][kk], acc[mf][nf], 0, 0, 0);
    __builtin_amdgcn_s_setprio(0);
    pbar();
#pragma unroll
    for (int mf = 0; mf < 4; ++mf) {
      const int r = 64 + mf * 16 + (lane & 15);
      a[mf][0] = *(const bf16x8*)(myA + r * 128 + xc0);
      a[mf][1] = *(const bf16x8*)(myA + r * 128 + xc1);
    }
    stage(p4 + 8);
    stage(p4 + 9);
    pbar();
    __builtin_amdgcn_s_setprio(1);
#pragma unroll
    for (int mf = 0; mf < 4; ++mf)
#pragma unroll
      for (int nf = 0; nf < 4; ++nf)
#pragma unroll
        for (int kk = 0; kk < 2; ++kk)
          acc[mf + 4][nf] = __builtin_amdgcn_mfma_f32_16x16x32_bf16(
              a[mf][kk], b[nf][kk], acc[mf + 4][nf], 0, 0, 0);
    __builtin_amdgcn_s_setprio(0);
    asm volatile("s_waitcnt vmcnt(4)" ::: "memory");
    pbar();
  }

#pragma unroll
  for (int mf = 0; mf < 8; ++mf) {
#pragma unroll
    for (int j = 0; j < 4; ++j) {
      int row = m0 + wr * 128 + mf * 16 + ((lane >> 4) << 2) + j;
#pragma unroll
      for (int nf = 0; nf < 4; ++nf) {
        int col = n0 + wc * 64 + nf * 16 + (lane & 15);
        float v = acc[mf][nf][j] + p.bias[col];
        p.out[(size_t)row * p.Nout + col] = f2bf(v);
      }
    }
  }
}

// ---------------- VQ 8-phase GEMM + fused argmin (128x256 tile) ----------------
struct GV {
  const unsigned short* A;
  const unsigned short* Bt;
  const float* cnorm;
  float* cval;
  int* cidx;
};

__global__ __launch_bounds__(512, 2) void vq8_k(GV p) {
  __shared__ __align__(16) unsigned short lds[49152];  // 96 KiB
  const int tid = threadIdx.x, lane = tid & 63, wid = tid >> 6;
  const int wr = wid >> 2, wc = wid & 3;
  const int m0 = blockIdx.x * 128, n0 = blockIdx.y * 256;
  const int sw = ((lane & 7) ^ (lane >> 3)) * 8;
  const int xc0 = ((lane >> 4) ^ (lane & 7)) * 16;
  const int xc1 = (((lane >> 4) | 4) ^ (lane & 7)) * 16;
  const int K = 2048;

  int rcA[2];
#pragma unroll
  for (int h = 0; h < 2; ++h)
    rcA[h] = (m0 + h * 64 + wid * 8 + (lane >> 3)) * K;
  int rcB[2][2];
#pragma unroll
  for (int h = 0; h < 2; ++h)
#pragma unroll
    for (int i = 0; i < 2; ++i)
      rcB[h][i] = (n0 + h * 128 + wid * 16 + i * 8 + (lane >> 3)) * K;

  auto stage = [&](int j) {
    if (j >= 128) return;
    const int T = j >> 2, type = j & 3;
    unsigned short* reg = &lds[(T & 1) * 24576];
    const int ko = (T << 6) + sw;
    if (type < 2) {
      gload_lds16(p.A + rcA[type] + ko, reg + type * 4096 + wid * 512);
    } else {
      unsigned short* d = reg + 8192 + (type - 2) * 8192 + wid * 1024;
      gload_lds16(p.Bt + rcB[type - 2][0] + ko, d);
      gload_lds16(p.Bt + rcB[type - 2][1] + ko, d + 512);
    }
  };

  f32x4 acc[4][4];
#pragma unroll
  for (int i = 0; i < 4; ++i)
#pragma unroll
    for (int j = 0; j < 4; ++j) acc[i][j] = (f32x4){0.f, 0.f, 0.f, 0.f};

#pragma unroll
  for (int j = 0; j < 6; ++j) stage(j);
  asm volatile("s_waitcnt vmcnt(2)" ::: "memory");
  pbar();

  bf16x8 a[4][2], b[4][2];
  for (int t = 0; t < 32; ++t) {
    const char* reg = (const char*)&lds[(t & 1) * 24576];
    const char* myA = reg + wr * 8192;
    const char* myB = reg + 16384 + (wc >> 1) * 16384;
    const int p4 = t << 2;
#pragma unroll
    for (int mf = 0; mf < 4; ++mf) {
      const int r = mf * 16 + (lane & 15);
      a[mf][0] = *(const bf16x8*)(myA + r * 128 + xc0);
      a[mf][1] = *(const bf16x8*)(myA + r * 128 + xc1);
    }
#pragma unroll
    for (int nf = 0; nf < 4; ++nf) {
      const int c = (wc & 1) * 64 + nf * 16 + (lane & 15);
      b[nf][0] = *(const bf16x8*)(myB + c * 128 + xc0);
      b[nf][1] = *(const bf16x8*)(myB + c * 128 + xc1);
    }
    stage(p4 + 6);
    stage(p4 + 7);
    pbar();
    __builtin_amdgcn_s_setprio(1);
#pragma unroll
    for (int mf = 0; mf < 4; ++mf)
#pragma unroll
      for (int nf = 0; nf < 2; ++nf)
#pragma unroll
        for (int kk = 0; kk < 2; ++kk)
          acc[mf][nf] = __builtin_amdgcn_mfma_f32_16x16x32_bf16(
              a[mf][kk], b[nf][kk], acc[mf][nf], 0, 0, 0);
    __builtin_amdgcn_s_setprio(0);
    pbar();
    stage(p4 + 8);
    stage(p4 + 9);
    pbar();
    __builtin_amdgcn_s_setprio(1);
#pragma unroll
    for (int mf = 0; mf < 4; ++mf)
#pragma unroll
      for (int nf = 2; nf < 4; ++nf)
#pragma unroll
        for (int kk = 0; kk < 2; ++kk)
          acc[mf][nf] = __builtin_amdgcn_mfma_f32_16x16x32_bf16(
              a[mf][kk], b[nf][kk], acc[mf][nf], 0, 0, 0);
    __builtin_amdgcn_s_setprio(0);
    asm volatile("s_waitcnt vmcnt(2)" ::: "memory");
    pbar();
  }

  __syncthreads();
  float* sV = (float*)lds;
  int* sI = (int*)(sV + 512);
  float cn[4];
#pragma unroll
  for (int nf = 0; nf < 4; ++nf)
    cn[nf] = p.cnorm[n0 + wc * 64 + nf * 16 + (lane & 15)];
#pragma unroll
  for (int mf = 0; mf < 4; ++mf) {
#pragma unroll
    for (int j = 0; j < 4; ++j) {
      float bv = 3.4e38f;
      int bi = 0x7fffffff;
#pragma unroll
      for (int nf = 0; nf < 4; ++nf) {
        int col = n0 + wc * 64 + nf * 16 + (lane & 15);
        float d = cn[nf] - 2.f * acc[mf][nf][j];
        if (d < bv) { bv = d; bi = col; }
      }
#pragma unroll
      for (int w = 1; w <= 8; w <<= 1) {
        float ov = __shfl_xor(bv, w, 64);
        int oi = __shfl_xor(bi, w, 64);
        if (ov < bv || (ov == bv && oi < bi)) { bv = ov; bi = oi; }
      }
      int lrow = wr * 64 + mf * 16 + ((lane >> 4) << 2) + j;
      if ((lane & 15) == 0) { sV[lrow * 4 + wc] = bv; sI[lrow * 4 + wc] = bi; }
    }
  }
  __syncthreads();
  if (tid < 128) {
    float bv = sV[tid * 4];
    int bi = sI[tid * 4];
#pragma unroll
    for (int c = 1; c < 4; ++c) {
      float v = sV[tid * 4 + c];
      int i2 = sI[tid * 4 + c];
      if (v < bv) { bv = v; bi = i2; }
    }
    p.cval[(size_t)(m0 + tid) * 4 + blockIdx.y] = bv;
    p.cidx[(size_t)(m0 + tid) * 4 + blockIdx.y] = bi;
  }
}

// ---------------- fused final-argmin + loss partial ----------------
__global__ __launch_bounds__(256) void lossz2_k(const unsigned short* __restrict__ zf,
                                                const float* __restrict__ cval,
                                                const int* __restrict__ cidx,
                                                int* __restrict__ idx,
                                                float* __restrict__ part) {
  int m = blockIdx.x;
  int tid = threadIdx.x;
  bf16x8 av = ((const bf16x8*)(zf + (size_t)m * 2048))[tid];
  float s = 0.f;
#pragma unroll
  for (int i = 0; i < 8; ++i) {
    float z = bf2f((unsigned short)av[i]);
    s += z * z;
  }
  __shared__ float red[4];
  for (int off = 32; off > 0; off >>= 1) s += __shfl_down(s, off, 64);
  int lane = tid & 63, wid = tid >> 6;
  if (lane == 0) red[wid] = s;
  __syncthreads();
  if (tid == 0) {
    float bv = cval[(size_t)m * 4];
    int bi = cidx[(size_t)m * 4];
#pragma unroll
    for (int j = 1; j < 4; ++j) {
      float v = cval[(size_t)m * 4 + j];
      int i2 = cidx[(size_t)m * 4 + j];
      if (v < bv) { bv = v; bi = i2; }
    }
    idx[m] = bi;
    part[m] = red[0] + red[1] + red[2] + red[3] + bv;
  }
}

__global__ __launch_bounds__(256) void loss_final_k(const float* __restrict__ part,
                                                    float* __restrict__ out) {
  int tid = threadIdx.x;
  float s = 0.f;
  for (int i = tid; i < 8192; i += 256) s += part[i];
  __shared__ float red[4];
  for (int off = 32; off > 0; off >>= 1) s += __shfl_down(s, off, 64);
  if ((tid & 63) == 0) red[tid >> 6] = s;
  __syncthreads();
  if (tid == 0) out[0] = 1.25f * (red[0] + red[1] + red[2] + red[3]) / 16777216.f;
}

// ---------------- deconv1 via codebook factorization ----------------
__global__ __launch_bounds__(256) void dc1gather_k(const float* __restrict__ V,
                                                   const int* __restrict__ idx,
                                                   const float* __restrict__ bias,
                                                   unsigned short* __restrict__ h3) {
  int b = blockIdx.x >> 6;
  int oy = blockIdx.x & 63;
  int co = threadIdx.x & 127;
  int xh = threadIdx.x >> 7;
  __shared__ int sIdx[2][32];
  int iyA = (oy + 1) >> 1, kyA = (oy + 1) & 1;
  int iyB = iyA - 1, kyB = kyA + 2;
  if (threadIdx.x < 64) {
    int which = threadIdx.x >> 5;
    int ix = threadIdx.x & 31;
    int iy = which ? iyB : iyA;
    sIdx[which][ix] = (iy >= 0 && iy < 32) ? idx[(b << 10) + (iy << 5) + ix] : -1;
  }
  __syncthreads();
  float bb = bias[co];
  for (int xi = 0; xi < 32; ++xi) {
    int ox = xh * 32 + xi;
    int ixA = (ox + 1) >> 1, kxA = (ox + 1) & 1;
    int ixB = ixA - 1, kxB = kxA + 2;
    float s = bb;
    int kAA = (ixA < 32) ? sIdx[0][ixA] : -1;
    if (kAA >= 0) s += V[((size_t)(kAA * 16 + kyA * 4 + kxA)) * 128 + co];
    int kAB = (ixB >= 0) ? sIdx[0][ixB] : -1;
    if (kAB >= 0) s += V[((size_t)(kAB * 16 + kyA * 4 + kxB)) * 128 + co];
    int kBA = (ixA < 32) ? sIdx[1][ixA] : -1;
    if (kBA >= 0) s += V[((size_t)(kBA * 16 + kyB * 4 + kxA)) * 128 + co];
    int kBB = (ixB >= 0) ? sIdx[1][ixB] : -1;
    if (kBB >= 0) s += V[((size_t)(kBB * 16 + kyB * 4 + kxB)) * 128 + co];
    s = s > 0.f ? s : 0.f;
    h3[((size_t)(b * 66 + oy + 1) * 66 + (ox + 1)) * 128 + co] = f2bf(s);
  }
}

// ---------------- deconv3 (128->1) + sigmoid, LDS-row-staged ----------------
__global__ __launch_bounds__(256) void deconv3_k(const unsigned short* __restrict__ h4,
                                                 const float* __restrict__ wd,
                                                 const float* __restrict__ b3,
                                                 float* __restrict__ out) {
  __shared__ __align__(16) char sRow[2 * 130 * 272];
  __shared__ float sW[2048];
  const int tid = threadIdx.x;
  const int b = blockIdx.x >> 8, oy = blockIdx.x & 255;
  const int py = oy & 1, uy = oy >> 1;
  const int g0 = uy + py;
  for (int i = tid; i < 2048; i += 256) sW[i] = wd[i];
  for (int g = tid; g < 4160; g += 256) {
    int r = (g >= 2080) ? 1 : 0;
    int gg = g - r * 2080;
    int px = gg >> 4, k = gg & 15;
    const bf16x8* src =
        (const bf16x8*)(h4 + (((size_t)(b * 130 + g0 + r) * 130 + px) << 7) + k * 8);
    *(bf16x8*)(sRow + r * 35360 + px * 272 + k * 16) = *src;
  }
  __syncthreads();
  const int ox = tid;
  const int pxp = ox & 1, ux = ox >> 1;
  const int z = py * 2 + pxp;
  float s = b3[0];
#pragma unroll
  for (int ty = 0; ty < 2; ++ty) {
#pragma unroll
    for (int tx = 0; tx < 2; ++tx) {
      int ixp = ux + 1 + pxp - tx;
      const char* base = sRow + (1 - ty) * 35360 + ixp * 272;
      const float* wp = &sW[z * 512 + (ty * 2 + tx) * 128];
#pragma unroll
      for (int k = 0; k < 16; ++k) {
        bf16x8 v = *(const bf16x8*)(base + k * 16);
#pragma unroll
        for (int i = 0; i < 8; ++i)
          s += bf2f((unsigned short)v[i]) * wp[k * 8 + i];
      }
    }
  }
  out[(size_t)blockIdx.x * 256 + ox] = 1.f / (1.f + __expf(-s));
}

// ---------------- launch ----------------
extern "C" void kernel_launch(void* const* d_in, const int* in_sizes, int n_in,
                              void* d_out, int out_size, void* d_ws, size_t ws_size,
                              hipStream_t stream) {
  const float* x = (const float*)d_in[0];
  const float* ew1 = (const float*)d_in[1];
  const float* eb1 = (const float*)d_in[2];
  const float* ew2 = (const float*)d_in[3];
  const float* eb2 = (const float*)d_in[4];
  const float* ew3 = (const float*)d_in[5];
  const float* eb3 = (const float*)d_in[6];
  const float* cb = (const float*)d_in[7];
  const float* dw1 = (const float*)d_in[8];
  const float* db1 = (const float*)d_in[9];
  const float* dw2 = (const float*)d_in[10];
  const float* db2 = (const float*)d_in[11];
  const float* dw3 = (const float*)d_in[12];
  const float* db3 = (const float*)d_in[13];
  float* out = (float*)d_out;

  char* w = (char*)d_ws;
  size_t off = 0;
  auto alloc = [&](size_t bytes) {
    char* p = w + off;
    off = (off + bytes + 255) & ~(size_t)255;
    return p;
  };
  const size_t sz_h1 = 8ull * 130 * 130 * 128 * 2;  // 34.6 MB
  const size_t sz_h2 = 8ull * 66 * 66 * 128 * 2;    // 8.9 MB
  const size_t sz_zf = 8192ull * 2048 * 2;          // 33.6 MB
  unsigned short* h1 = (unsigned short*)alloc(sz_h1);
  unsigned short* h2 = (unsigned short*)alloc(sz_h2);
  unsigned short* zf = (unsigned short*)alloc(sz_zf);
  unsigned short* cbb = (unsigned short*)alloc(1024ull * 2048 * 2);
  float* cnorm = (float*)alloc(1024 * 4);
  int* idx = (int*)alloc(8192 * 4);
  unsigned short* h4 = (unsigned short*)alloc(sz_h1);
  unsigned short* bt2 = (unsigned short*)alloc(128ull * 2048 * 2);
  unsigned short* bt3 = (unsigned short*)alloc(2048ull * 2048 * 2);
  unsigned short* btw1 = (unsigned short*)alloc(2048ull * 2048 * 2);
  unsigned short* btd2 = (unsigned short*)alloc(4ull * 128 * 512 * 2);
  float* V = (float*)alloc(1024ull * 16 * 128 * 4);  // 8.4 MB
  float* lpart = (float*)alloc(8192 * 4);
  float* wd3 = (float*)alloc(2048 * 4);
  unsigned short* h3 = (unsigned short*)alloc(sz_h2);
  float* cval = (float*)alloc(8192ull * 4 * 4);
  int* cidx = (int*)alloc(8192ull * 4 * 4);

  halo_k<<<6208, 256, 0, stream>>>(h1, h2, h3, h4);
  packT_k<<<4352, 256, 0, stream>>>(ew2, ew3, dw1, dw2, bt2, bt3, btw1, btd2);
  pack_cb<<<1025, 256, 0, stream>>>(cb, dw3, cbb, cnorm, wd3);
  conv1_k<<<1024, 256, 0, stream>>>(x, ew1, eb1, h1);

  // V = codebook . w1-factor: M=1024, N=2048, K=2048 (2-phase pipelined)
  GP pcw = {cbb, btw1, nullptr, V, 2048, 11, 0, 0, 0, 0, 0, 0,
            2048, 2048, 0, 0, 0, 0};
  gemmp_k<GM_FLAT, EP_F32, 0><<<dim3(16, 16, 1), 256, 0, stream>>>(pcw);

  // conv2: M=32768(64x64), N=128, K=2048 (2-phase pipelined)
  GP p2 = {h1, bt2, eb2, h2, 2048, 7, 6, 6, 130, 130 * 130 * 128, 66, 66,
           128, 2048, 0, 0, 0, 0};
  gemmp_k<GM_CONV, EP_PM, 1><<<dim3(512, 1, 1), 256, 0, stream>>>(p2);

  // conv3 (2-phase 256^2): M=8192(32x32), N=2048, K=2048 -> z_flat
  G2 g3 = {h2, bt3, eb3, zf, 2048, 66, 66 * 66 * 128, 2048};
  gemm256_k<GM_CONV><<<dim3(32, 8, 1), 512, 0, stream>>>(g3);

  // VQ (8-phase 128x256) + fused per-block argmin
  GV pv = {zf, cbb, cnorm, cval, cidx};
  vq8_k<<<dim3(64, 4, 1), 512, 0, stream>>>(pv);

  // final argmin + loss partials fused
  lossz2_k<<<8192, 256, 0, stream>>>(zf, cval, cidx, idx, lpart);
  loss_final_k<<<1, 256, 0, stream>>>(lpart, out + 524288);

  // deconv1 = gather from V by idx (+bias, ReLU) -> h3 padded
  dc1gather_k<<<512, 256, 0, stream>>>(V, idx, db1, h3);

  // deconv2: per class M=32768(64x64), N=128, K=512, BM=128 (high occupancy)
  GP pd2 = {h3, btd2, db2, h4, 512, 7, 6, 6, 66, 66 * 66 * 128, 130, 130,
            128, 512, 128 * 512, 2, 0, 0};
  gemm_k<128, GM_DECONV, EP_PM, 1><<<dim3(256, 1, 4), 256, 0, stream>>>(pd2);

  deconv3_k<<<2048, 256, 0, stream>>>(h4, wd3, db3, out);
  (void)in_sizes; (void)n_in; (void)out_size; (void)ws_size;
}